// Round 7
// baseline (490.845 us; speedup 1.0000x reference)
//
#include <hip/hip_runtime.h>
#include <math.h>

#define T_TOKENS 8192
#define HID      4096
#define NEXP     512
#define TOPK     12
#define RSCALE   2.5f

// ---------------- shared helpers (verified round 1) ----------------

__device__ __forceinline__ unsigned int fkey(float f) {
    unsigned int u = __float_as_uint(f);
    return (u & 0x80000000u) ? ~u : (u | 0x80000000u);  // monotonic float->uint
}

__device__ __forceinline__ float pick8(const float* p, int j) {
    float v = p[0];
    if (j == 1) v = p[1];
    if (j == 2) v = p[2];
    if (j == 3) v = p[3];
    if (j == 4) v = p[4];
    if (j == 5) v = p[5];
    if (j == 6) v = p[6];
    if (j == 7) v = p[7];
    return v;
}

// Completion counters for the fused topk (one per m_grp). Zero-initialized
// (.bss) and re-zeroed by wconv_kernel each iteration (stream-ordered before
// gemm2), so no workspace bytes are consumed and tiers are unchanged.
__device__ int g_cnt[128];

// ================== fp16x3 split-precision common ==================
// x = xh + 2^-12 xl + O(2^-22 x)   (RNE hi, RNE scaled residual)
// logits*64 = accH(xh*wh) + 2^-12 * accC(xh*wl + xl*wh), W pre-scaled *64.

typedef __attribute__((ext_vector_type(8))) _Float16 f16x8;
typedef __attribute__((ext_vector_type(4))) float    f32x4;

#define BM   128         // fallback-kernel M tile
#define BM2  64          // gemm2 M tile (2 blocks/CU)
#define BN   128
#define BKF  32          // fp32 k per slab
#define ROWB 144         // padded X LDS row: 64 B hi | 16 B pad | 64 B lo

// float4 -> 4 packed hi halves (uint2) + 4 packed scaled-lo halves (uint2), RNE
__device__ __forceinline__ void cvt4(const float4 f, uint2& h, uint2& l) {
    _Float16 h0 = (_Float16)f.x, h1 = (_Float16)f.y;
    _Float16 h2 = (_Float16)f.z, h3 = (_Float16)f.w;
    float r0 = (f.x - (float)h0) * 4096.f;
    float r1 = (f.y - (float)h1) * 4096.f;
    float r2 = (f.z - (float)h2) * 4096.f;
    float r3 = (f.w - (float)h3) * 4096.f;
    _Float16 l0 = (_Float16)r0, l1 = (_Float16)r1;
    _Float16 l2 = (_Float16)r2, l3 = (_Float16)r3;
    union P { _Float16 q[2]; unsigned int u; } p;
    p.q[0] = h0; p.q[1] = h1; h.x = p.u;
    p.q[0] = h2; p.q[1] = h3; h.y = p.u;
    p.q[0] = l0; p.q[1] = l1; l.x = p.u;
    p.q[0] = l2; p.q[1] = l3; l.y = p.u;
}

__device__ __forceinline__ void load_lds16(const void* g, void* l) {
    __builtin_amdgcn_global_load_lds((const __attribute__((address_space(1))) void*)g,
                                     (__attribute__((address_space(3))) void*)l,
                                     16, 0, 0);
}

// ---------------- per-token biased top-12 (verified math, rounds 1/3/5) ----
// Shared by the fused gemm2 epilogue and the standalone topk kernel so the
// selection arithmetic is bitwise identical in both paths.

__device__ __forceinline__ void topk_token(const float* __restrict__ logits,
                                           const float br[8],
                                           float* __restrict__ out,
                                           int tok, int lane)
{
    const float4 z0 = *(const float4*)&logits[(size_t)tok * NEXP + 4 * lane];
    const float4 z1 = *(const float4*)&logits[(size_t)tok * NEXP + 256 + 4 * lane];
    float z[8] = {z0.x, z0.y, z0.z, z0.w, z1.x, z1.y, z1.z, z1.w};

    float m = z[0];
    #pragma unroll
    for (int j = 1; j < 8; j++) m = fmaxf(m, z[j]);
    #pragma unroll
    for (int off = 32; off >= 1; off >>= 1) m = fmaxf(m, __shfl_xor(m, off));

    float p[8];
    float s = 0.f;
    #pragma unroll
    for (int j = 0; j < 8; j++) { p[j] = expf(z[j] - m); s += p[j]; }
    #pragma unroll
    for (int off = 32; off >= 1; off >>= 1) s += __shfl_xor(s, off);
    const float inv = 1.f / s;

    float pb[8];
    unsigned long long kj[8];
    #pragma unroll
    for (int j = 0; j < 8; j++) {
        pb[j] = p[j] * inv;
        const int e = (j < 4) ? (4 * lane + j) : (256 + 4 * lane + (j - 4));
        kj[j] = ((unsigned long long)fkey(pb[j] + br[j]) << 32) |
                (unsigned long long)(unsigned int)(1023 - e);
    }
    unsigned long long lk = kj[0];
    #pragma unroll
    for (int j = 1; j < 8; j++) lk = (kj[j] > lk) ? kj[j] : lk;

    for (int kk = 0; kk < TOPK; kk++) {
        unsigned long long key = lk;
        #pragma unroll
        for (int off = 32; off >= 1; off >>= 1) {
            unsigned long long o = __shfl_xor(key, off);
            key = (o > key) ? o : key;
        }
        const int estar = 1023 - (int)(unsigned int)(key & 0xffffffffull);

        int lstar, jstar;
        if (estar < 256) { lstar = estar >> 2;         jstar = estar & 3; }
        else             { lstar = (estar - 256) >> 2; jstar = 4 + ((estar - 256) & 3); }

        const float pj   = pick8(pb, jstar);
        const float psel = __shfl(pj, lstar);

        if (lane == lstar) {
            if (jstar == 0) kj[0] = 0ull;
            if (jstar == 1) kj[1] = 0ull;
            if (jstar == 2) kj[2] = 0ull;
            if (jstar == 3) kj[3] = 0ull;
            if (jstar == 4) kj[4] = 0ull;
            if (jstar == 5) kj[5] = 0ull;
            if (jstar == 6) kj[6] = 0ull;
            if (jstar == 7) kj[7] = 0ull;
            unsigned long long nl = kj[0];
            #pragma unroll
            for (int j = 1; j < 8; j++) nl = (kj[j] > nl) ? kj[j] : nl;
            lk = nl;
        }

        if (lane == 0) {
            out[(size_t)tok * TOPK + kk] = psel * RSCALE;
            out[(size_t)T_TOKENS * TOPK + (size_t)tok * TOPK + kk] = (float)estar;
        }
    }
}

// ================== Kernel 0: W -> fp16 planes, DMA-ready swizzled layout ==================
// Wp slot (kc, e, p) 16 B at ((kc*512+e)*8+p)*16 holds group g = p ^ (e&7):
//   g<4: hi fp16 of 64*W[e][kc*32+g*8 .. +7];  g>=4: lo plane of same k-range.
// Bitwise identical to cvt4's planes (same RNE formulas).
// Also re-zeroes the fused-topk completion counters (stream order: before gemm2).

__global__ void wconv_kernel(const float* __restrict__ W, uint4* __restrict__ Wp) {
    if (blockIdx.x == 0 && threadIdx.x < 128) g_cnt[threadIdx.x] = 0;

    const int gid = blockIdx.x * 256 + threadIdx.x;   // 524288 total
    const int e  = gid >> 10;
    const int kc = (gid >> 3) & 127;
    const int p  = gid & 7;
    const int g  = p ^ (e & 7);
    const int kbase = kc * 32 + (g & 3) * 8;
    const float* src = W + (size_t)e * HID + kbase;
    const float4 f0 = *(const float4*)src;
    const float4 f1 = *(const float4*)(src + 4);
    const float v[8] = {f0.x, f0.y, f0.z, f0.w, f1.x, f1.y, f1.z, f1.w};

    union H { _Float16 f; unsigned short u; } cv;
    unsigned short h[8];
    if (g < 4) {
        #pragma unroll
        for (int j = 0; j < 8; j++) { cv.f = (_Float16)(v[j] * 64.f); h[j] = cv.u; }
    } else {
        #pragma unroll
        for (int j = 0; j < 8; j++) {
            const float w64 = v[j] * 64.f;
            const _Float16 hh = (_Float16)w64;
            cv.f = (_Float16)((w64 - (float)hh) * 4096.f);
            h[j] = cv.u;
        }
    }
    union O { unsigned short q[8]; uint4 u; } o;
    #pragma unroll
    for (int j = 0; j < 8; j++) o.q[j] = h[j];
    Wp[(size_t)(kc * 512 + e) * 8 + p] = o.u;
}

// ================== Kernel 1: GEMM (round-5 verified, BK=64) + fused topk ==================
// GEMM body is byte-identical to round 5 (best measured: 134us, MfmaUtil 33%).
// New: fused biased top-12 epilogue. Each of the 4 n_grp blocks of an m_grp
// writes its logits quadrant, release-fences, and bumps g_cnt[m_grp]; the
// LAST arriver (old==3) acquire-fences and runs top-12 for the 64 tokens
// (4 waves x 16 tokens, same topk_token math -> bitwise-identical outputs).
// No spinning -> no deadlock possible regardless of scheduling; correctness
// uses device-scope fences, not the XCD swizzle (which only makes the logits
// re-read L2-local).

__launch_bounds__(256, 2)
__global__ void gemm2_kernel(const float* __restrict__ X,
                             const uint4* __restrict__ Wp,
                             float* __restrict__ logits,
                             const float* __restrict__ bias,
                             float* __restrict__ out)
{
    __shared__ __align__(16) unsigned char Xs[2][BM2 * ROWB];   // 2 slabs x 9216 B
    __shared__ __align__(16) unsigned char Ws[2][BN * 128];     // 2 slabs x 16384 B

    const int tid  = threadIdx.x;
    const int lane = tid & 63;
    const int wave = tid >> 6;

    // XCD-aware swizzle (round-1, verified FETCH=98MB): XCD x owns m_groups
    // x*16..x*16+15, all 4 n_groups co-resident -> X tile hits its L2 once.
    const int x8    = blockIdx.x & 7;
    const int i64   = blockIdx.x >> 3;        // 0..63
    const int m_grp = x8 * 16 + (i64 >> 2);   // 0..127
    const int n_grp = i64 & 3;
    const int tok0  = m_grp * BM2;
    const int e0    = n_grp * BN;

    const int waveM = (wave >> 1) * 32;       // wave owns 32 tokens x 64 experts
    const int waveN = (wave & 1) * 64;
    const int m16   = lane & 15;
    const int q     = lane >> 4;

    const float* Xb = X + (size_t)tok0 * HID;

    // W DMA addressing: per-lane global src, wave-uniform LDS dst; both advance
    // 1024 B per 8-row segment. Content is pre-swizzled by wconv.
    const char* wsrc = (const char*)Wp + (size_t)(e0 + wave * 32) * 128 + lane * 16;
    const int   wofs = (wave * 32) * 128;

    // X staging map: s in 0..3 -> slab = s>>1, row = (s&1)*32 + tid>>3, grp = tid&7
    const int xrow = tid >> 3;
    const int xgrp = tid & 7;

    // ---- prefetch X slabs for j=0 into regs ----
    float4 px[4];
    #pragma unroll
    for (int s = 0; s < 4; s++) {
        const int row = (s & 1) * 32 + xrow;
        px[s] = *(const float4*)&Xb[(size_t)row * HID + (s >> 1) * BKF + xgrp * 4];
    }

    f32x4 accH[2][4], accC[2][4];
    #pragma unroll
    for (int mi = 0; mi < 2; mi++)
        #pragma unroll
        for (int ni = 0; ni < 4; ni++) { accH[mi][ni] = (f32x4)0.f; accC[mi][ni] = (f32x4)0.f; }

    #pragma unroll 1
    for (int j = 0; j < 64; j++) {
        __syncthreads();   // prior iteration done reading LDS

        // async W planes -> LDS, both slabs (issued first: max DMA cover)
        #pragma unroll
        for (int sl = 0; sl < 2; sl++)
            #pragma unroll
            for (int s = 0; s < 4; s++)
                load_lds16(wsrc + (size_t)(2 * j + sl) * (512 * 128) + s * 1024,
                           &Ws[sl][wofs + s * 1024]);

        // X: convert prefetched regs -> padded LDS planes, both slabs
        #pragma unroll
        for (int s = 0; s < 4; s++) {
            const int row = (s & 1) * 32 + xrow;
            uint2 h, l;
            cvt4(px[s], h, l);
            *(uint2*)(&Xs[s >> 1][row * ROWB + xgrp * 8])      = h;
            *(uint2*)(&Xs[s >> 1][row * ROWB + 80 + xgrp * 8]) = l;
        }
        __syncthreads();   // drains vmcnt (W DMA) + LDS writes

        // prefetch next X slabs (covered by the 48-MFMA phase)
        if (j + 1 < 64) {
            #pragma unroll
            for (int s = 0; s < 4; s++) {
                const int row = (s & 1) * 32 + xrow;
                px[s] = *(const float4*)&Xb[(size_t)row * HID + (j + 1) * 64 + (s >> 1) * BKF + xgrp * 4];
            }
        }

        // fragments + MFMA, slab 0 then slab 1 (= kc 2j, 2j+1: order preserved)
        #pragma unroll
        for (int sl = 0; sl < 2; sl++) {
            f16x8 Ah[2], Al[2], Bh[4], Bl[4];
            #pragma unroll
            for (int mi = 0; mi < 2; mi++) {
                const unsigned char* p = &Xs[sl][(waveM + mi * 16 + m16) * ROWB + q * 16];
                Ah[mi] = *(const f16x8*)p;
                Al[mi] = *(const f16x8*)(p + 80);
            }
            #pragma unroll
            for (int ni = 0; ni < 4; ni++) {
                const int row = waveN + ni * 16 + m16;
                const unsigned char* pr = &Ws[sl][row * 128];
                const int r7 = row & 7;
                Bh[ni] = *(const f16x8*)(pr + ((q ^ r7) * 16));
                Bl[ni] = *(const f16x8*)(pr + (((4 | q) ^ r7) * 16));
            }
            #pragma unroll
            for (int mi = 0; mi < 2; mi++)
                #pragma unroll
                for (int ni = 0; ni < 4; ni++) {
                    accH[mi][ni] = __builtin_amdgcn_mfma_f32_16x16x32_f16(Ah[mi], Bh[ni], accH[mi][ni], 0, 0, 0);
                    accC[mi][ni] = __builtin_amdgcn_mfma_f32_16x16x32_f16(Ah[mi], Bl[ni], accC[mi][ni], 0, 0, 0);
                    accC[mi][ni] = __builtin_amdgcn_mfma_f32_16x16x32_f16(Al[mi], Bh[ni], accC[mi][ni], 0, 0, 0);
                }
        }
    }

    // C/D layout (verified m89/m91): col = lane&15, row = q*4 + reg
    #pragma unroll
    for (int mi = 0; mi < 2; mi++)
        #pragma unroll
        for (int ni = 0; ni < 4; ni++) {
            const int e = e0 + waveN + ni * 16 + m16;
            #pragma unroll
            for (int r = 0; r < 4; r++) {
                const int token = tok0 + waveM + mi * 16 + q * 4 + r;
                logits[(size_t)token * NEXP + e] =
                    (accH[mi][ni][r] + accC[mi][ni][r] * (1.f / 4096.f)) * (1.f / 64.f);
            }
        }

    // ---------------- fused biased top-12 (last arriving block only) --------
    __threadfence();                      // release this block's logits stores
    __syncthreads();                      // all threads fenced before arrival
    __shared__ int lastFlag;
    if (tid == 0) lastFlag = (atomicAdd(&g_cnt[m_grp], 1) == 3);
    __syncthreads();
    if (!lastFlag) return;
    __threadfence();                      // acquire before reading peers' logits

    const float4 bs0 = *(const float4*)&bias[4 * lane];
    const float4 bs1 = *(const float4*)&bias[256 + 4 * lane];
    const float br[8] = {bs0.x, bs0.y, bs0.z, bs0.w, bs1.x, bs1.y, bs1.z, bs1.w};

    // 4 waves x 16 tokens = the m_grp's 64 tokens; logits are L2-hot (same XCD).
    for (int t = 0; t < 16; t++)
        topk_token(logits, br, out, tok0 + wave * 16 + t, lane);
}

// ================== Fallback GEMM (round-3, verified): X+W converted in-kernel ==================

__launch_bounds__(256, 1)
__global__ void gemm_kernel(const float* __restrict__ X,
                            const float* __restrict__ W,
                            float* __restrict__ logits)
{
    __shared__ __align__(16) unsigned char Xs[BM * ROWB];
    __shared__ __align__(16) unsigned char Ws[BN * ROWB];

    const int tid  = threadIdx.x;
    const int lane = tid & 63;
    const int wave = tid >> 6;

    const int n_grp = blockIdx.x & 3;
    const int m_grp = blockIdx.x >> 2;
    const int tok0  = m_grp * BM;
    const int e0    = n_grp * BN;

    const int waveM = (wave >> 1) * 64;
    const int waveN = (wave & 1) * 64;
    const int m16   = lane & 15;
    const int q     = lane >> 4;

    const float* Xb = X + (size_t)tok0 * HID;
    const float* Wb = W + (size_t)e0 * HID;

    float4 px[4], pw[4];
    #pragma unroll
    for (int s = 0; s < 4; s++) {
        const int flat = s * 256 + tid;
        const int row = flat >> 3, grp = flat & 7;
        px[s] = *(const float4*)&Xb[(size_t)row * HID + grp * 4];
        pw[s] = *(const float4*)&Wb[(size_t)row * HID + grp * 4];
    }

    f32x4 accH[4][4], accC[4][4];
    #pragma unroll
    for (int mi = 0; mi < 4; mi++)
        #pragma unroll
        for (int ni = 0; ni < 4; ni++) { accH[mi][ni] = (f32x4)0.f; accC[mi][ni] = (f32x4)0.f; }

    #pragma unroll 1
    for (int k0 = 0; k0 < HID; k0 += BKF) {
        #pragma unroll
        for (int s = 0; s < 4; s++) {
            const int flat = s * 256 + tid;
            const int row = flat >> 3, grp = flat & 7;
            uint2 h, l;
            cvt4(px[s], h, l);
            *(uint2*)(Xs + row * ROWB + grp * 8)      = h;
            *(uint2*)(Xs + row * ROWB + 80 + grp * 8) = l;
            const float4 w64 = make_float4(pw[s].x * 64.f, pw[s].y * 64.f,
                                           pw[s].z * 64.f, pw[s].w * 64.f);
            cvt4(w64, h, l);
            *(uint2*)(Ws + row * ROWB + grp * 8)      = h;
            *(uint2*)(Ws + row * ROWB + 80 + grp * 8) = l;
        }
        __syncthreads();

        if (k0 + BKF < HID) {
            #pragma unroll
            for (int s = 0; s < 4; s++) {
                const int flat = s * 256 + tid;
                const int row = flat >> 3, grp = flat & 7;
                px[s] = *(const float4*)&Xb[(size_t)row * HID + (k0 + BKF) + grp * 4];
                pw[s] = *(const float4*)&Wb[(size_t)row * HID + (k0 + BKF) + grp * 4];
            }
        }

        f16x8 Ah[4], Al[4], Bh[4], Bl[4];
        #pragma unroll
        for (int mi = 0; mi < 4; mi++) {
            const unsigned char* p = Xs + (waveM + mi * 16 + m16) * ROWB + q * 16;
            Ah[mi] = *(const f16x8*)p;
            Al[mi] = *(const f16x8*)(p + 80);
        }
        #pragma unroll
        for (int ni = 0; ni < 4; ni++) {
            const unsigned char* p = Ws + (waveN + ni * 16 + m16) * ROWB + q * 16;
            Bh[ni] = *(const f16x8*)p;
            Bl[ni] = *(const f16x8*)(p + 80);
        }

        #pragma unroll
        for (int mi = 0; mi < 4; mi++)
            #pragma unroll
            for (int ni = 0; ni < 4; ni++) {
                accH[mi][ni] = __builtin_amdgcn_mfma_f32_16x16x32_f16(Ah[mi], Bh[ni], accH[mi][ni], 0, 0, 0);
                accC[mi][ni] = __builtin_amdgcn_mfma_f32_16x16x32_f16(Ah[mi], Bl[ni], accC[mi][ni], 0, 0, 0);
                accC[mi][ni] = __builtin_amdgcn_mfma_f32_16x16x32_f16(Al[mi], Bh[ni], accC[mi][ni], 0, 0, 0);
            }
        __syncthreads();
    }

    #pragma unroll
    for (int mi = 0; mi < 4; mi++)
        #pragma unroll
        for (int ni = 0; ni < 4; ni++) {
            const int e = e0 + waveN + ni * 16 + m16;
            #pragma unroll
            for (int r = 0; r < 4; r++) {
                const int token = tok0 + waveM + mi * 16 + q * 4 + r;
                logits[(size_t)token * NEXP + e] =
                    (accH[mi][ni][r] + accC[mi][ni][r] * (1.f / 4096.f)) * (1.f / 64.f);
            }
        }
}

// ================== Kernel 2 (fallback tier): standalone topk ==================

__launch_bounds__(256, 4)
__global__ void topk_kernel(const float* __restrict__ logits,
                            const float* __restrict__ bias,
                            float* __restrict__ out)
{
    const int lane = threadIdx.x & 63;
    const int wave = threadIdx.x >> 6;
    const int tok  = blockIdx.x * 4 + wave;

    const float4 bs0 = *(const float4*)&bias[4 * lane];
    const float4 bs1 = *(const float4*)&bias[256 + 4 * lane];
    const float br[8] = {bs0.x, bs0.y, bs0.z, bs0.w, bs1.x, bs1.y, bs1.z, bs1.w};

    topk_token(logits, br, out, tok, lane);
}

// ================== Fallback: round-1 fused fp32 kernel (verified) ==================

#define TM   32
#define BK   16
#define EPAD (NEXP + 4)
#define XPAD 36

__launch_bounds__(256, 1)
__global__ void router_kernel(const float* __restrict__ X,
                              const float* __restrict__ W,
                              const float* __restrict__ bias,
                              float* __restrict__ out)
{
    __shared__ float Wsh[BK][EPAD];
    __shared__ float Xsh[BK][XPAD];

    const int tid  = threadIdx.x;
    const int lane = tid & 63;
    const int wave = tid >> 6;
    const int tok0 = blockIdx.x * TM;

    float acc[8][8];
    #pragma unroll
    for (int i = 0; i < 8; i++)
        #pragma unroll
        for (int j = 0; j < 8; j++) acc[i][j] = 0.f;

    const int xt = tid >> 4;
    const int xk = tid & 15;

    for (int k0 = 0; k0 < HID; k0 += BK) {
        #pragma unroll
        for (int r = 0; r < 2; r++) {
            int t = r * 16 + xt;
            Xsh[xk][t] = X[(size_t)(tok0 + t) * HID + k0 + xk];
        }
        #pragma unroll
        for (int r = 0; r < 8; r++) {
            int flat4 = r * 256 + tid;
            int e  = flat4 >> 2;
            int kq = (flat4 & 3) * 4;
            const float4 wv = *(const float4*)&W[(size_t)e * HID + k0 + kq];
            Wsh[kq + 0][e] = wv.x;
            Wsh[kq + 1][e] = wv.y;
            Wsh[kq + 2][e] = wv.z;
            Wsh[kq + 3][e] = wv.w;
        }
        __syncthreads();

        #pragma unroll
        for (int k = 0; k < BK; k++) {
            float4 b0 = *(const float4*)&Wsh[k][4 * lane];
            float4 b1 = *(const float4*)&Wsh[k][256 + 4 * lane];
            float4 a0 = *(const float4*)&Xsh[k][wave * 8];
            float4 a1 = *(const float4*)&Xsh[k][wave * 8 + 4];
            float a[8] = {a0.x, a0.y, a0.z, a0.w, a1.x, a1.y, a1.z, a1.w};
            float b[8] = {b0.x, b0.y, b0.z, b0.w, b1.x, b1.y, b1.z, b1.w};
            #pragma unroll
            for (int i = 0; i < 8; i++)
                #pragma unroll
                for (int j = 0; j < 8; j++)
                    acc[i][j] = fmaf(a[i], b[j], acc[i][j]);
        }
        __syncthreads();
    }

    const float4 bs0 = *(const float4*)&bias[4 * lane];
    const float4 bs1 = *(const float4*)&bias[256 + 4 * lane];
    const float br[8] = {bs0.x, bs0.y, bs0.z, bs0.w, bs1.x, bs1.y, bs1.z, bs1.w};

    for (int i = 0; i < 8; i++) {
        const int tok = tok0 + wave * 8 + i;

        float m = acc[i][0];
        #pragma unroll
        for (int j = 1; j < 8; j++) m = fmaxf(m, acc[i][j]);
        #pragma unroll
        for (int off = 32; off >= 1; off >>= 1) m = fmaxf(m, __shfl_xor(m, off));

        float p[8];
        float s = 0.f;
        #pragma unroll
        for (int j = 0; j < 8; j++) { p[j] = expf(acc[i][j] - m); s += p[j]; }
        #pragma unroll
        for (int off = 32; off >= 1; off >>= 1) s += __shfl_xor(s, off);
        const float inv = 1.f / s;

        float pb[8], bb[8];
        #pragma unroll
        for (int j = 0; j < 8; j++) {
            pb[j] = p[j] * inv;
            bb[j] = pb[j] + br[j];
        }

        for (int kk = 0; kk < TOPK; kk++) {
            unsigned long long key = 0ull;
            #pragma unroll
            for (int j = 0; j < 8; j++) {
                int e = (j < 4) ? (4 * lane + j) : (256 + 4 * lane + (j - 4));
                unsigned long long k64 =
                    ((unsigned long long)fkey(bb[j]) << 32) |
                    (unsigned long long)(unsigned int)(1023 - e);
                key = (k64 > key) ? k64 : key;
            }
            #pragma unroll
            for (int off = 32; off >= 1; off >>= 1) {
                unsigned long long o = __shfl_xor(key, off);
                key = (o > key) ? o : key;
            }
            const int estar = 1023 - (int)(unsigned int)(key & 0xffffffffull);

            int lstar, jstar;
            if (estar < 256) { lstar = estar >> 2;         jstar = estar & 3; }
            else             { lstar = (estar - 256) >> 2; jstar = 4 + ((estar - 256) & 3); }

            const float pj   = pick8(pb, jstar);
            const float psel = __shfl(pj, lstar);

            if (lane == lstar) {
                if (jstar == 0) bb[0] = -INFINITY;
                if (jstar == 1) bb[1] = -INFINITY;
                if (jstar == 2) bb[2] = -INFINITY;
                if (jstar == 3) bb[3] = -INFINITY;
                if (jstar == 4) bb[4] = -INFINITY;
                if (jstar == 5) bb[5] = -INFINITY;
                if (jstar == 6) bb[6] = -INFINITY;
                if (jstar == 7) bb[7] = -INFINITY;
            }

            if (lane == 0) {
                out[(size_t)tok * TOPK + kk] = psel * RSCALE;
                out[(size_t)T_TOKENS * TOPK + (size_t)tok * TOPK + kk] = (float)estar;
            }
        }
    }
}

// ================== launcher ==================

extern "C" void kernel_launch(void* const* d_in, const int* in_sizes, int n_in,
                              void* d_out, int out_size, void* d_ws, size_t ws_size,
                              hipStream_t stream)
{
    const float* X    = (const float*)d_in[0];   // [8192, 4096]
    const float* W    = (const float*)d_in[1];   // [512, 4096]
    const float* bias = (const float*)d_in[2];   // [512]
    float* out = (float*)d_out;

    const size_t logits_bytes = (size_t)T_TOKENS * NEXP * sizeof(float);   // 16 MB
    const size_t wp_bytes     = (size_t)NEXP * HID * 4;                    // 8 MB (2 fp16 planes)

    if (ws_size >= logits_bytes + wp_bytes) {
        float* logits = (float*)d_ws;
        uint4* Wp     = (uint4*)((char*)d_ws + logits_bytes);
        wconv_kernel<<<dim3(2048), dim3(256), 0, stream>>>(W, Wp);
        gemm2_kernel<<<dim3(512), dim3(256), 0, stream>>>(X, Wp, logits, bias, out);
    } else if (ws_size >= logits_bytes) {
        float* logits = (float*)d_ws;
        gemm_kernel<<<dim3(256), dim3(256), 0, stream>>>(X, W, logits);
        topk_kernel<<<dim3(T_TOKENS / 4), dim3(256), 0, stream>>>(logits, bias, out);
    } else {
        router_kernel<<<dim3(T_TOKENS / TM), dim3(256), 0, stream>>>(X, W, bias, out);
    }
}

// Round 8
// 390.747 us; speedup vs baseline: 1.2562x; 1.2562x over previous
//
#include <hip/hip_runtime.h>
#include <math.h>

#define T_TOKENS 8192
#define HID      4096
#define NEXP     512
#define TOPK     12
#define RSCALE   2.5f

// ---------------- shared helpers (verified round 1) ----------------

__device__ __forceinline__ unsigned int fkey(float f) {
    unsigned int u = __float_as_uint(f);
    return (u & 0x80000000u) ? ~u : (u | 0x80000000u);  // monotonic float->uint
}

__device__ __forceinline__ float pick8(const float* p, int j) {
    float v = p[0];
    if (j == 1) v = p[1];
    if (j == 2) v = p[2];
    if (j == 3) v = p[3];
    if (j == 4) v = p[4];
    if (j == 5) v = p[5];
    if (j == 6) v = p[6];
    if (j == 7) v = p[7];
    return v;
}

// Grid-barrier counter for the fused kernel. Zero-init (.bss); re-zeroed by
// wconv_kernel each iteration (stream-ordered before gemm2_fused).
__device__ int g_sync;

// ================== fp16x3 split-precision common ==================
// x = xh + 2^-12 xl + O(2^-22 x)   (RNE hi, RNE scaled residual)
// logits*64 = accH(xh*wh) + 2^-12 * accC(xh*wl + xl*wh), W pre-scaled *64.

typedef __attribute__((ext_vector_type(8))) _Float16 f16x8;
typedef __attribute__((ext_vector_type(4))) float    f32x4;

#define BM   128         // fallback-kernel M tile
#define BM2  64          // gemm2 M tile (2 blocks/CU)
#define BN   128
#define BKF  32          // fp32 k per slab
#define ROWB 144         // padded X LDS row: 64 B hi | 16 B pad | 64 B lo

// float4 -> 4 packed hi halves (uint2) + 4 packed scaled-lo halves (uint2), RNE
__device__ __forceinline__ void cvt4(const float4 f, uint2& h, uint2& l) {
    _Float16 h0 = (_Float16)f.x, h1 = (_Float16)f.y;
    _Float16 h2 = (_Float16)f.z, h3 = (_Float16)f.w;
    float r0 = (f.x - (float)h0) * 4096.f;
    float r1 = (f.y - (float)h1) * 4096.f;
    float r2 = (f.z - (float)h2) * 4096.f;
    float r3 = (f.w - (float)h3) * 4096.f;
    _Float16 l0 = (_Float16)r0, l1 = (_Float16)r1;
    _Float16 l2 = (_Float16)r2, l3 = (_Float16)r3;
    union P { _Float16 q[2]; unsigned int u; } p;
    p.q[0] = h0; p.q[1] = h1; h.x = p.u;
    p.q[0] = h2; p.q[1] = h3; h.y = p.u;
    p.q[0] = l0; p.q[1] = l1; l.x = p.u;
    p.q[0] = l2; p.q[1] = l3; l.y = p.u;
}

__device__ __forceinline__ void load_lds16(const void* g, void* l) {
    __builtin_amdgcn_global_load_lds((const __attribute__((address_space(1))) void*)g,
                                     (__attribute__((address_space(3))) void*)l,
                                     16, 0, 0);
}

// ---------------- per-token biased top-12 (verified rounds 1/3/5) ----------

__device__ __forceinline__ void topk_token(const float* __restrict__ logits,
                                           const float br[8],
                                           float* __restrict__ out,
                                           int tok, int lane)
{
    const float4 z0 = *(const float4*)&logits[(size_t)tok * NEXP + 4 * lane];
    const float4 z1 = *(const float4*)&logits[(size_t)tok * NEXP + 256 + 4 * lane];
    float z[8] = {z0.x, z0.y, z0.z, z0.w, z1.x, z1.y, z1.z, z1.w};

    float m = z[0];
    #pragma unroll
    for (int j = 1; j < 8; j++) m = fmaxf(m, z[j]);
    #pragma unroll
    for (int off = 32; off >= 1; off >>= 1) m = fmaxf(m, __shfl_xor(m, off));

    float p[8];
    float s = 0.f;
    #pragma unroll
    for (int j = 0; j < 8; j++) { p[j] = expf(z[j] - m); s += p[j]; }
    #pragma unroll
    for (int off = 32; off >= 1; off >>= 1) s += __shfl_xor(s, off);
    const float inv = 1.f / s;

    float pb[8];
    unsigned long long kj[8];
    #pragma unroll
    for (int j = 0; j < 8; j++) {
        pb[j] = p[j] * inv;
        const int e = (j < 4) ? (4 * lane + j) : (256 + 4 * lane + (j - 4));
        kj[j] = ((unsigned long long)fkey(pb[j] + br[j]) << 32) |
                (unsigned long long)(unsigned int)(1023 - e);
    }
    unsigned long long lk = kj[0];
    #pragma unroll
    for (int j = 1; j < 8; j++) lk = (kj[j] > lk) ? kj[j] : lk;

    for (int kk = 0; kk < TOPK; kk++) {
        unsigned long long key = lk;
        #pragma unroll
        for (int off = 32; off >= 1; off >>= 1) {
            unsigned long long o = __shfl_xor(key, off);
            key = (o > key) ? o : key;
        }
        const int estar = 1023 - (int)(unsigned int)(key & 0xffffffffull);

        int lstar, jstar;
        if (estar < 256) { lstar = estar >> 2;         jstar = estar & 3; }
        else             { lstar = (estar - 256) >> 2; jstar = 4 + ((estar - 256) & 3); }

        const float pj   = pick8(pb, jstar);
        const float psel = __shfl(pj, lstar);

        if (lane == lstar) {
            if (jstar == 0) kj[0] = 0ull;
            if (jstar == 1) kj[1] = 0ull;
            if (jstar == 2) kj[2] = 0ull;
            if (jstar == 3) kj[3] = 0ull;
            if (jstar == 4) kj[4] = 0ull;
            if (jstar == 5) kj[5] = 0ull;
            if (jstar == 6) kj[6] = 0ull;
            if (jstar == 7) kj[7] = 0ull;
            unsigned long long nl = kj[0];
            #pragma unroll
            for (int j = 1; j < 8; j++) nl = (kj[j] > nl) ? kj[j] : nl;
            lk = nl;
        }

        if (lane == 0) {
            out[(size_t)tok * TOPK + kk] = psel * RSCALE;
            out[(size_t)T_TOKENS * TOPK + (size_t)tok * TOPK + kk] = (float)estar;
        }
    }
}

// ================== Kernel 0: W -> fp16 planes, DMA-ready swizzled layout ==================
// Wp slot (kc, e, p) 16 B at ((kc*512+e)*8+p)*16 holds group g = p ^ (e&7):
//   g<4: hi fp16 of 64*W[e][kc*32+g*8 .. +7];  g>=4: lo plane of same k-range.
// Also re-zeroes the grid-barrier counter (stream order: before gemm2_fused).

__global__ void wconv_kernel(const float* __restrict__ W, uint4* __restrict__ Wp) {
    if (blockIdx.x == 0 && threadIdx.x == 0) g_sync = 0;

    const int gid = blockIdx.x * 256 + threadIdx.x;   // 524288 total
    const int e  = gid >> 10;
    const int kc = (gid >> 3) & 127;
    const int p  = gid & 7;
    const int g  = p ^ (e & 7);
    const int kbase = kc * 32 + (g & 3) * 8;
    const float* src = W + (size_t)e * HID + kbase;
    const float4 f0 = *(const float4*)src;
    const float4 f1 = *(const float4*)(src + 4);
    const float v[8] = {f0.x, f0.y, f0.z, f0.w, f1.x, f1.y, f1.z, f1.w};

    union H { _Float16 f; unsigned short u; } cv;
    unsigned short h[8];
    if (g < 4) {
        #pragma unroll
        for (int j = 0; j < 8; j++) { cv.f = (_Float16)(v[j] * 64.f); h[j] = cv.u; }
    } else {
        #pragma unroll
        for (int j = 0; j < 8; j++) {
            const float w64 = v[j] * 64.f;
            const _Float16 hh = (_Float16)w64;
            cv.f = (_Float16)((w64 - (float)hh) * 4096.f);
            h[j] = cv.u;
        }
    }
    union O { unsigned short q[8]; uint4 u; } o;
    #pragma unroll
    for (int j = 0; j < 8; j++) o.q[j] = h[j];
    Wp[(size_t)(kc * 512 + e) * 8 + p] = o.u;
}

// ================== GEMM body (round-5 verified, BK=64, 134us) ==================
// Shared verbatim by the fused kernel and the standalone fallback so the
// accumulation order (kc ascending, mi/ni/{H,C,C}) stays bitwise-identical.

__device__ __forceinline__ void gemm2_body(const float* __restrict__ X,
                                           const uint4* __restrict__ Wp,
                                           float* __restrict__ logits,
                                           int& tok0_out, int& n_grp_out)
{
    __shared__ __align__(16) unsigned char Xs[2][BM2 * ROWB];   // 2 slabs x 9216 B
    __shared__ __align__(16) unsigned char Ws[2][BN * 128];     // 2 slabs x 16384 B

    const int tid  = threadIdx.x;
    const int lane = tid & 63;
    const int wave = tid >> 6;

    // XCD-aware swizzle (round-1, verified FETCH=98MB): XCD x owns m_groups
    // x*16..x*16+15, all 4 n_groups co-resident -> X tile hits its L2 once.
    const int x8    = blockIdx.x & 7;
    const int i64   = blockIdx.x >> 3;        // 0..63
    const int m_grp = x8 * 16 + (i64 >> 2);   // 0..127
    const int n_grp = i64 & 3;
    const int tok0  = m_grp * BM2;
    const int e0    = n_grp * BN;
    tok0_out = tok0; n_grp_out = n_grp;

    const int waveM = (wave >> 1) * 32;       // wave owns 32 tokens x 64 experts
    const int waveN = (wave & 1) * 64;
    const int m16   = lane & 15;
    const int q     = lane >> 4;

    const float* Xb = X + (size_t)tok0 * HID;

    const char* wsrc = (const char*)Wp + (size_t)(e0 + wave * 32) * 128 + lane * 16;
    const int   wofs = (wave * 32) * 128;

    const int xrow = tid >> 3;
    const int xgrp = tid & 7;

    float4 px[4];
    #pragma unroll
    for (int s = 0; s < 4; s++) {
        const int row = (s & 1) * 32 + xrow;
        px[s] = *(const float4*)&Xb[(size_t)row * HID + (s >> 1) * BKF + xgrp * 4];
    }

    f32x4 accH[2][4], accC[2][4];
    #pragma unroll
    for (int mi = 0; mi < 2; mi++)
        #pragma unroll
        for (int ni = 0; ni < 4; ni++) { accH[mi][ni] = (f32x4)0.f; accC[mi][ni] = (f32x4)0.f; }

    #pragma unroll 1
    for (int j = 0; j < 64; j++) {
        __syncthreads();   // prior iteration done reading LDS

        // async W planes -> LDS, both slabs (issued first: max DMA cover)
        #pragma unroll
        for (int sl = 0; sl < 2; sl++)
            #pragma unroll
            for (int s = 0; s < 4; s++)
                load_lds16(wsrc + (size_t)(2 * j + sl) * (512 * 128) + s * 1024,
                           &Ws[sl][wofs + s * 1024]);

        // X: convert prefetched regs -> padded LDS planes, both slabs
        #pragma unroll
        for (int s = 0; s < 4; s++) {
            const int row = (s & 1) * 32 + xrow;
            uint2 h, l;
            cvt4(px[s], h, l);
            *(uint2*)(&Xs[s >> 1][row * ROWB + xgrp * 8])      = h;
            *(uint2*)(&Xs[s >> 1][row * ROWB + 80 + xgrp * 8]) = l;
        }
        __syncthreads();   // drains vmcnt (W DMA) + LDS writes

        // prefetch next X slabs (covered by the 48-MFMA phase)
        if (j + 1 < 64) {
            #pragma unroll
            for (int s = 0; s < 4; s++) {
                const int row = (s & 1) * 32 + xrow;
                px[s] = *(const float4*)&Xb[(size_t)row * HID + (j + 1) * 64 + (s >> 1) * BKF + xgrp * 4];
            }
        }

        // fragments + MFMA, slab 0 then slab 1 (= kc 2j, 2j+1: order preserved)
        #pragma unroll
        for (int sl = 0; sl < 2; sl++) {
            f16x8 Ah[2], Al[2], Bh[4], Bl[4];
            #pragma unroll
            for (int mi = 0; mi < 2; mi++) {
                const unsigned char* p = &Xs[sl][(waveM + mi * 16 + m16) * ROWB + q * 16];
                Ah[mi] = *(const f16x8*)p;
                Al[mi] = *(const f16x8*)(p + 80);
            }
            #pragma unroll
            for (int ni = 0; ni < 4; ni++) {
                const int row = waveN + ni * 16 + m16;
                const unsigned char* pr = &Ws[sl][row * 128];
                const int r7 = row & 7;
                Bh[ni] = *(const f16x8*)(pr + ((q ^ r7) * 16));
                Bl[ni] = *(const f16x8*)(pr + (((4 | q) ^ r7) * 16));
            }
            #pragma unroll
            for (int mi = 0; mi < 2; mi++)
                #pragma unroll
                for (int ni = 0; ni < 4; ni++) {
                    accH[mi][ni] = __builtin_amdgcn_mfma_f32_16x16x32_f16(Ah[mi], Bh[ni], accH[mi][ni], 0, 0, 0);
                    accC[mi][ni] = __builtin_amdgcn_mfma_f32_16x16x32_f16(Ah[mi], Bl[ni], accC[mi][ni], 0, 0, 0);
                    accC[mi][ni] = __builtin_amdgcn_mfma_f32_16x16x32_f16(Al[mi], Bh[ni], accC[mi][ni], 0, 0, 0);
                }
        }
    }

    // C/D layout (verified m89/m91): col = lane&15, row = q*4 + reg
    #pragma unroll
    for (int mi = 0; mi < 2; mi++)
        #pragma unroll
        for (int ni = 0; ni < 4; ni++) {
            const int e = e0 + waveN + ni * 16 + m16;
            #pragma unroll
            for (int r = 0; r < 4; r++) {
                const int token = tok0 + waveM + mi * 16 + q * 4 + r;
                logits[(size_t)token * NEXP + e] =
                    (accH[mi][ni][r] + accC[mi][ni][r] * (1.f / 4096.f)) * (1.f / 64.f);
            }
        }
}

// ================== Kernel 1a: fused GEMM + grid barrier + full-width topk ====
// R7 lesson: the fused tail must keep FULL parallelism. After the barrier all
// 512 blocks (2048 waves) run topk, 4 tokens/wave -- same parallel shape as
// the standalone kernel, but zero extra dispatch slot (worth ~48us, measured
// R5 vs R7 bucket: 181 -> 133us).
// Barrier safety: grid = 512 = 2 x 256 CUs, __launch_bounds__(256,2) caps
// VGPR<=256, LDS 51.2KB <= 80KB -> all blocks co-resident (guide-sanctioned
// capacity pattern; R5's 21% occupancy = 2 blocks/CU confirms) -> spin cannot
// deadlock. Visibility: each block's tid0 does an agent-scope ACQ_REL RMW
// (wbl2 publishes its XCD L2, where __syncthreads already drained its stores);
// readers pass the count only after ALL RMWs; acquire fence before reads.

__launch_bounds__(256, 2)
__global__ void gemm2_fused(const float* __restrict__ X,
                            const uint4* __restrict__ Wp,
                            float* __restrict__ logits,
                            const float* __restrict__ bias,
                            float* __restrict__ out)
{
    int tok0, n_grp;
    gemm2_body(X, Wp, logits, tok0, n_grp);

    // ---- grid barrier ----
    __syncthreads();                        // all logits stores drained to L2
    if (threadIdx.x == 0) {
        __hip_atomic_fetch_add(&g_sync, 1, __ATOMIC_ACQ_REL, __HIP_MEMORY_SCOPE_AGENT);
        while (__hip_atomic_load(&g_sync, __ATOMIC_RELAXED, __HIP_MEMORY_SCOPE_AGENT) < 512)
            __builtin_amdgcn_s_sleep(2);
    }
    __syncthreads();
    __threadfence();                        // acquire: fresh reads of peers' logits

    // ---- topk phase: 16 tokens/block (own m_grp slice -> L2-hot), 4/wave ----
    const int lane = threadIdx.x & 63;
    const int wave = threadIdx.x >> 6;

    const float4 bs0 = *(const float4*)&bias[4 * lane];
    const float4 bs1 = *(const float4*)&bias[256 + 4 * lane];
    const float br[8] = {bs0.x, bs0.y, bs0.z, bs0.w, bs1.x, bs1.y, bs1.z, bs1.w};

    const int tbase = tok0 + n_grp * 16 + wave * 4;
    #pragma unroll 1
    for (int t = 0; t < 4; t++)
        topk_token(logits, br, out, tbase + t, lane);
}

// ================== Kernel 1b (fallback tier): standalone GEMM ==================

__launch_bounds__(256, 2)
__global__ void gemm2_kernel(const float* __restrict__ X,
                             const uint4* __restrict__ Wp,
                             float* __restrict__ logits)
{
    int tok0, n_grp;
    gemm2_body(X, Wp, logits, tok0, n_grp);
}

// ================== Fallback GEMM (round-3, verified): X+W converted in-kernel ==================

__launch_bounds__(256, 1)
__global__ void gemm_kernel(const float* __restrict__ X,
                            const float* __restrict__ W,
                            float* __restrict__ logits)
{
    __shared__ __align__(16) unsigned char Xs[BM * ROWB];
    __shared__ __align__(16) unsigned char Ws[BN * ROWB];

    const int tid  = threadIdx.x;
    const int lane = tid & 63;
    const int wave = tid >> 6;

    const int n_grp = blockIdx.x & 3;
    const int m_grp = blockIdx.x >> 2;
    const int tok0  = m_grp * BM;
    const int e0    = n_grp * BN;

    const int waveM = (wave >> 1) * 64;
    const int waveN = (wave & 1) * 64;
    const int m16   = lane & 15;
    const int q     = lane >> 4;

    const float* Xb = X + (size_t)tok0 * HID;
    const float* Wb = W + (size_t)e0 * HID;

    float4 px[4], pw[4];
    #pragma unroll
    for (int s = 0; s < 4; s++) {
        const int flat = s * 256 + tid;
        const int row = flat >> 3, grp = flat & 7;
        px[s] = *(const float4*)&Xb[(size_t)row * HID + grp * 4];
        pw[s] = *(const float4*)&Wb[(size_t)row * HID + grp * 4];
    }

    f32x4 accH[4][4], accC[4][4];
    #pragma unroll
    for (int mi = 0; mi < 4; mi++)
        #pragma unroll
        for (int ni = 0; ni < 4; ni++) { accH[mi][ni] = (f32x4)0.f; accC[mi][ni] = (f32x4)0.f; }

    #pragma unroll 1
    for (int k0 = 0; k0 < HID; k0 += BKF) {
        #pragma unroll
        for (int s = 0; s < 4; s++) {
            const int flat = s * 256 + tid;
            const int row = flat >> 3, grp = flat & 7;
            uint2 h, l;
            cvt4(px[s], h, l);
            *(uint2*)(Xs + row * ROWB + grp * 8)      = h;
            *(uint2*)(Xs + row * ROWB + 80 + grp * 8) = l;
            const float4 w64 = make_float4(pw[s].x * 64.f, pw[s].y * 64.f,
                                           pw[s].z * 64.f, pw[s].w * 64.f);
            cvt4(w64, h, l);
            *(uint2*)(Ws + row * ROWB + grp * 8)      = h;
            *(uint2*)(Ws + row * ROWB + 80 + grp * 8) = l;
        }
        __syncthreads();

        if (k0 + BKF < HID) {
            #pragma unroll
            for (int s = 0; s < 4; s++) {
                const int flat = s * 256 + tid;
                const int row = flat >> 3, grp = flat & 7;
                px[s] = *(const float4*)&Xb[(size_t)row * HID + (k0 + BKF) + grp * 4];
                pw[s] = *(const float4*)&Wb[(size_t)row * HID + (k0 + BKF) + grp * 4];
            }
        }

        f16x8 Ah[4], Al[4], Bh[4], Bl[4];
        #pragma unroll
        for (int mi = 0; mi < 4; mi++) {
            const unsigned char* p = Xs + (waveM + mi * 16 + m16) * ROWB + q * 16;
            Ah[mi] = *(const f16x8*)p;
            Al[mi] = *(const f16x8*)(p + 80);
        }
        #pragma unroll
        for (int ni = 0; ni < 4; ni++) {
            const unsigned char* p = Ws + (waveN + ni * 16 + m16) * ROWB + q * 16;
            Bh[ni] = *(const f16x8*)p;
            Bl[ni] = *(const f16x8*)(p + 80);
        }

        #pragma unroll
        for (int mi = 0; mi < 4; mi++)
            #pragma unroll
            for (int ni = 0; ni < 4; ni++) {
                accH[mi][ni] = __builtin_amdgcn_mfma_f32_16x16x32_f16(Ah[mi], Bh[ni], accH[mi][ni], 0, 0, 0);
                accC[mi][ni] = __builtin_amdgcn_mfma_f32_16x16x32_f16(Ah[mi], Bl[ni], accC[mi][ni], 0, 0, 0);
                accC[mi][ni] = __builtin_amdgcn_mfma_f32_16x16x32_f16(Al[mi], Bh[ni], accC[mi][ni], 0, 0, 0);
            }
        __syncthreads();
    }

    #pragma unroll
    for (int mi = 0; mi < 4; mi++)
        #pragma unroll
        for (int ni = 0; ni < 4; ni++) {
            const int e = e0 + waveN + ni * 16 + m16;
            #pragma unroll
            for (int r = 0; r < 4; r++) {
                const int token = tok0 + waveM + mi * 16 + q * 4 + r;
                logits[(size_t)token * NEXP + e] =
                    (accH[mi][ni][r] + accC[mi][ni][r] * (1.f / 4096.f)) * (1.f / 64.f);
            }
        }
}

// ================== Kernel 2 (fallback tier): standalone topk ==================

__launch_bounds__(256, 4)
__global__ void topk_kernel(const float* __restrict__ logits,
                            const float* __restrict__ bias,
                            float* __restrict__ out)
{
    const int lane = threadIdx.x & 63;
    const int wave = threadIdx.x >> 6;
    const int tok  = blockIdx.x * 4 + wave;

    const float4 bs0 = *(const float4*)&bias[4 * lane];
    const float4 bs1 = *(const float4*)&bias[256 + 4 * lane];
    const float br[8] = {bs0.x, bs0.y, bs0.z, bs0.w, bs1.x, bs1.y, bs1.z, bs1.w};

    topk_token(logits, br, out, tok, lane);
}

// ================== Fallback: round-1 fused fp32 kernel (verified) ==================

#define TM   32
#define BK   16
#define EPAD (NEXP + 4)
#define XPAD 36

__launch_bounds__(256, 1)
__global__ void router_kernel(const float* __restrict__ X,
                              const float* __restrict__ W,
                              const float* __restrict__ bias,
                              float* __restrict__ out)
{
    __shared__ float Wsh[BK][EPAD];
    __shared__ float Xsh[BK][XPAD];

    const int tid  = threadIdx.x;
    const int lane = tid & 63;
    const int wave = tid >> 6;
    const int tok0 = blockIdx.x * TM;

    float acc[8][8];
    #pragma unroll
    for (int i = 0; i < 8; i++)
        #pragma unroll
        for (int j = 0; j < 8; j++) acc[i][j] = 0.f;

    const int xt = tid >> 4;
    const int xk = tid & 15;

    for (int k0 = 0; k0 < HID; k0 += BK) {
        #pragma unroll
        for (int r = 0; r < 2; r++) {
            int t = r * 16 + xt;
            Xsh[xk][t] = X[(size_t)(tok0 + t) * HID + k0 + xk];
        }
        #pragma unroll
        for (int r = 0; r < 8; r++) {
            int flat4 = r * 256 + tid;
            int e  = flat4 >> 2;
            int kq = (flat4 & 3) * 4;
            const float4 wv = *(const float4*)&W[(size_t)e * HID + k0 + kq];
            Wsh[kq + 0][e] = wv.x;
            Wsh[kq + 1][e] = wv.y;
            Wsh[kq + 2][e] = wv.z;
            Wsh[kq + 3][e] = wv.w;
        }
        __syncthreads();

        #pragma unroll
        for (int k = 0; k < BK; k++) {
            float4 b0 = *(const float4*)&Wsh[k][4 * lane];
            float4 b1 = *(const float4*)&Wsh[k][256 + 4 * lane];
            float4 a0 = *(const float4*)&Xsh[k][wave * 8];
            float4 a1 = *(const float4*)&Xsh[k][wave * 8 + 4];
            float a[8] = {a0.x, a0.y, a0.z, a0.w, a1.x, a1.y, a1.z, a1.w};
            float b[8] = {b0.x, b0.y, b0.z, b0.w, b1.x, b1.y, b1.z, b1.w};
            #pragma unroll
            for (int i = 0; i < 8; i++)
                #pragma unroll
                for (int j = 0; j < 8; j++)
                    acc[i][j] = fmaf(a[i], b[j], acc[i][j]);
        }
        __syncthreads();
    }

    const float4 bs0 = *(const float4*)&bias[4 * lane];
    const float4 bs1 = *(const float4*)&bias[256 + 4 * lane];
    const float br[8] = {bs0.x, bs0.y, bs0.z, bs0.w, bs1.x, bs1.y, bs1.z, bs1.w};

    for (int i = 0; i < 8; i++) {
        const int tok = tok0 + wave * 8 + i;

        float m = acc[i][0];
        #pragma unroll
        for (int j = 1; j < 8; j++) m = fmaxf(m, acc[i][j]);
        #pragma unroll
        for (int off = 32; off >= 1; off >>= 1) m = fmaxf(m, __shfl_xor(m, off));

        float p[8];
        float s = 0.f;
        #pragma unroll
        for (int j = 0; j < 8; j++) { p[j] = expf(acc[i][j] - m); s += p[j]; }
        #pragma unroll
        for (int off = 32; off >= 1; off >>= 1) s += __shfl_xor(s, off);
        const float inv = 1.f / s;

        float pb[8], bb[8];
        #pragma unroll
        for (int j = 0; j < 8; j++) {
            pb[j] = p[j] * inv;
            bb[j] = pb[j] + br[j];
        }

        for (int kk = 0; kk < TOPK; kk++) {
            unsigned long long key = 0ull;
            #pragma unroll
            for (int j = 0; j < 8; j++) {
                int e = (j < 4) ? (4 * lane + j) : (256 + 4 * lane + (j - 4));
                unsigned long long k64 =
                    ((unsigned long long)fkey(bb[j]) << 32) |
                    (unsigned long long)(unsigned int)(1023 - e);
                key = (k64 > key) ? k64 : key;
            }
            #pragma unroll
            for (int off = 32; off >= 1; off >>= 1) {
                unsigned long long o = __shfl_xor(key, off);
                key = (o > key) ? o : key;
            }
            const int estar = 1023 - (int)(unsigned int)(key & 0xffffffffull);

            int lstar, jstar;
            if (estar < 256) { lstar = estar >> 2;         jstar = estar & 3; }
            else             { lstar = (estar - 256) >> 2; jstar = 4 + ((estar - 256) & 3); }

            const float pj   = pick8(pb, jstar);
            const float psel = __shfl(pj, lstar);

            if (lane == lstar) {
                if (jstar == 0) bb[0] = -INFINITY;
                if (jstar == 1) bb[1] = -INFINITY;
                if (jstar == 2) bb[2] = -INFINITY;
                if (jstar == 3) bb[3] = -INFINITY;
                if (jstar == 4) bb[4] = -INFINITY;
                if (jstar == 5) bb[5] = -INFINITY;
                if (jstar == 6) bb[6] = -INFINITY;
                if (jstar == 7) bb[7] = -INFINITY;
            }

            if (lane == 0) {
                out[(size_t)tok * TOPK + kk] = psel * RSCALE;
                out[(size_t)T_TOKENS * TOPK + (size_t)tok * TOPK + kk] = (float)estar;
            }
        }
    }
}

// ================== launcher ==================

extern "C" void kernel_launch(void* const* d_in, const int* in_sizes, int n_in,
                              void* d_out, int out_size, void* d_ws, size_t ws_size,
                              hipStream_t stream)
{
    const float* X    = (const float*)d_in[0];   // [8192, 4096]
    const float* W    = (const float*)d_in[1];   // [512, 4096]
    const float* bias = (const float*)d_in[2];   // [512]
    float* out = (float*)d_out;

    const size_t logits_bytes = (size_t)T_TOKENS * NEXP * sizeof(float);   // 16 MB
    const size_t wp_bytes     = (size_t)NEXP * HID * 4;                    // 8 MB (2 fp16 planes)

    if (ws_size >= logits_bytes + wp_bytes) {
        float* logits = (float*)d_ws;
        uint4* Wp     = (uint4*)((char*)d_ws + logits_bytes);
        wconv_kernel<<<dim3(2048), dim3(256), 0, stream>>>(W, Wp);
        gemm2_fused<<<dim3(512), dim3(256), 0, stream>>>(X, Wp, logits, bias, out);
    } else if (ws_size >= logits_bytes) {
        float* logits = (float*)d_ws;
        gemm_kernel<<<dim3(256), dim3(256), 0, stream>>>(X, W, logits);
        topk_kernel<<<dim3(T_TOKENS / 4), dim3(256), 0, stream>>>(logits, bias, out);
    } else {
        router_kernel<<<dim3(T_TOKENS / TM), dim3(256), 0, stream>>>(X, W, bias, out);
    }
}

// Round 10
// 314.869 us; speedup vs baseline: 1.5589x; 1.2410x over previous
//
#include <hip/hip_runtime.h>
#include <math.h>

#define T_TOKENS 8192
#define HID      4096
#define NEXP     512
#define TOPK     12
#define RSCALE   2.5f

// ---------------- shared helpers (verified round 1) ----------------

__device__ __forceinline__ unsigned int fkey(float f) {
    unsigned int u = __float_as_uint(f);
    return (u & 0x80000000u) ? ~u : (u | 0x80000000u);  // monotonic float->uint
}

__device__ __forceinline__ float pick8(const float* p, int j) {
    float v = p[0];
    if (j == 1) v = p[1];
    if (j == 2) v = p[2];
    if (j == 3) v = p[3];
    if (j == 4) v = p[4];
    if (j == 5) v = p[5];
    if (j == 6) v = p[6];
    if (j == 7) v = p[7];
    return v;
}

// ================== fp16x3 split-precision common ==================
// x = xh + 2^-12 xl + O(2^-22 x)   (RNE hi, RNE scaled residual)
// logits*64 = accH(xh*wh) + 2^-12 * accC(xh*wl + xl*wh), W pre-scaled *64.

typedef __attribute__((ext_vector_type(8))) _Float16 f16x8;
typedef __attribute__((ext_vector_type(4))) float    f32x4;

#define BM   128         // fallback-kernel M tile
#define BM2  64          // gemm2 M tile (2 blocks/CU)
#define BN   128
#define BKF  32          // fp32 k per slab
#define ROWB 144         // padded X LDS row: 64 B hi | 16 B pad | 64 B lo

// float4 -> 4 packed hi halves (uint2) + 4 packed scaled-lo halves (uint2), RNE
__device__ __forceinline__ void cvt4(const float4 f, uint2& h, uint2& l) {
    _Float16 h0 = (_Float16)f.x, h1 = (_Float16)f.y;
    _Float16 h2 = (_Float16)f.z, h3 = (_Float16)f.w;
    float r0 = (f.x - (float)h0) * 4096.f;
    float r1 = (f.y - (float)h1) * 4096.f;
    float r2 = (f.z - (float)h2) * 4096.f;
    float r3 = (f.w - (float)h3) * 4096.f;
    _Float16 l0 = (_Float16)r0, l1 = (_Float16)r1;
    _Float16 l2 = (_Float16)r2, l3 = (_Float16)r3;
    union P { _Float16 q[2]; unsigned int u; } p;
    p.q[0] = h0; p.q[1] = h1; h.x = p.u;
    p.q[0] = h2; p.q[1] = h3; h.y = p.u;
    p.q[0] = l0; p.q[1] = l1; l.x = p.u;
    p.q[0] = l2; p.q[1] = l3; l.y = p.u;
}

__device__ __forceinline__ void load_lds16(const void* g, void* l) {
    __builtin_amdgcn_global_load_lds((const __attribute__((address_space(1))) void*)g,
                                     (__attribute__((address_space(3))) void*)l,
                                     16, 0, 0);
}

// ================== Kernel 0: W -> fp16 planes, DMA-ready swizzled layout ==================
// Wp slot (kc, e, p) 16 B at ((kc*512+e)*8+p)*16 holds group g = p ^ (e&7):
//   g<4: hi fp16 of 64*W[e][kc*32+g*8 .. +7];  g>=4: lo plane of same k-range.
// Bitwise identical to cvt4's planes (same RNE formulas).

__global__ void wconv_kernel(const float* __restrict__ W, uint4* __restrict__ Wp) {
    const int gid = blockIdx.x * 256 + threadIdx.x;   // 524288 total
    const int e  = gid >> 10;
    const int kc = (gid >> 3) & 127;
    const int p  = gid & 7;
    const int g  = p ^ (e & 7);
    const int kbase = kc * 32 + (g & 3) * 8;
    const float* src = W + (size_t)e * HID + kbase;
    const float4 f0 = *(const float4*)src;
    const float4 f1 = *(const float4*)(src + 4);
    const float v[8] = {f0.x, f0.y, f0.z, f0.w, f1.x, f1.y, f1.z, f1.w};

    union H { _Float16 f; unsigned short u; } cv;
    unsigned short h[8];
    if (g < 4) {
        #pragma unroll
        for (int j = 0; j < 8; j++) { cv.f = (_Float16)(v[j] * 64.f); h[j] = cv.u; }
    } else {
        #pragma unroll
        for (int j = 0; j < 8; j++) {
            const float w64 = v[j] * 64.f;
            const _Float16 hh = (_Float16)w64;
            cv.f = (_Float16)((w64 - (float)hh) * 4096.f);
            h[j] = cv.u;
        }
    }
    union O { unsigned short q[8]; uint4 u; } o;
    #pragma unroll
    for (int j = 0; j < 8; j++) o.q[j] = h[j];
    Wp[(size_t)(kc * 512 + e) * 8 + p] = o.u;
}

// ================== Kernel 1: GEMM (round-1 structure, BK=64 — session best) ==================
// Verified round 5: 134us, MfmaUtil 33.4%, FETCH 98.3MB. TWO 32-k slabs per
// barrier pair -> 64 iterations; halves the per-iteration drain stalls vs
// BK=32 and doubles px-prefetch cover. BK=96 (200us) and all sync
// restructurings (184/215/205us) measured worse. Sync structure, swizzle
// (X-sharing: all 4 n_grps of an m_grp on one XCD), and per-output
// kc-ascending accumulation order preserved -> bitwise-identical logits.

__launch_bounds__(256, 2)
__global__ void gemm2_kernel(const float* __restrict__ X,
                             const uint4* __restrict__ Wp,
                             float* __restrict__ logits)
{
    __shared__ __align__(16) unsigned char Xs[2][BM2 * ROWB];   // 2 slabs x 9216 B
    __shared__ __align__(16) unsigned char Ws[2][BN * 128];     // 2 slabs x 16384 B

    const int tid  = threadIdx.x;
    const int lane = tid & 63;
    const int wave = tid >> 6;

    // XCD-aware swizzle (round-1, verified FETCH=98MB): XCD x owns m_groups
    // x*16..x*16+15, all 4 n_groups co-resident -> X tile hits its L2 once.
    const int x8    = blockIdx.x & 7;
    const int i64   = blockIdx.x >> 3;        // 0..63
    const int m_grp = x8 * 16 + (i64 >> 2);   // 0..127
    const int n_grp = i64 & 3;
    const int tok0  = m_grp * BM2;
    const int e0    = n_grp * BN;

    const int waveM = (wave >> 1) * 32;       // wave owns 32 tokens x 64 experts
    const int waveN = (wave & 1) * 64;
    const int m16   = lane & 15;
    const int q     = lane >> 4;

    const float* Xb = X + (size_t)tok0 * HID;

    // W DMA addressing: per-lane global src, wave-uniform LDS dst; both advance
    // 1024 B per 8-row segment. Content is pre-swizzled by wconv.
    const char* wsrc = (const char*)Wp + (size_t)(e0 + wave * 32) * 128 + lane * 16;
    const int   wofs = (wave * 32) * 128;

    // X staging map: s in 0..3 -> slab = s>>1, row = (s&1)*32 + tid>>3, grp = tid&7
    const int xrow = tid >> 3;
    const int xgrp = tid & 7;

    // ---- prefetch X slabs for j=0 into regs ----
    float4 px[4];
    #pragma unroll
    for (int s = 0; s < 4; s++) {
        const int row = (s & 1) * 32 + xrow;
        px[s] = *(const float4*)&Xb[(size_t)row * HID + (s >> 1) * BKF + xgrp * 4];
    }

    f32x4 accH[2][4], accC[2][4];
    #pragma unroll
    for (int mi = 0; mi < 2; mi++)
        #pragma unroll
        for (int ni = 0; ni < 4; ni++) { accH[mi][ni] = (f32x4)0.f; accC[mi][ni] = (f32x4)0.f; }

    #pragma unroll 1
    for (int j = 0; j < 64; j++) {
        __syncthreads();   // prior iteration done reading LDS

        // async W planes -> LDS, both slabs (issued first: max DMA cover)
        #pragma unroll
        for (int sl = 0; sl < 2; sl++)
            #pragma unroll
            for (int s = 0; s < 4; s++)
                load_lds16(wsrc + (size_t)(2 * j + sl) * (512 * 128) + s * 1024,
                           &Ws[sl][wofs + s * 1024]);

        // X: convert prefetched regs -> padded LDS planes, both slabs
        #pragma unroll
        for (int s = 0; s < 4; s++) {
            const int row = (s & 1) * 32 + xrow;
            uint2 h, l;
            cvt4(px[s], h, l);
            *(uint2*)(&Xs[s >> 1][row * ROWB + xgrp * 8])      = h;
            *(uint2*)(&Xs[s >> 1][row * ROWB + 80 + xgrp * 8]) = l;
        }
        __syncthreads();   // drains vmcnt (W DMA) + LDS writes

        // prefetch next X slabs (covered by the 48-MFMA phase)
        if (j + 1 < 64) {
            #pragma unroll
            for (int s = 0; s < 4; s++) {
                const int row = (s & 1) * 32 + xrow;
                px[s] = *(const float4*)&Xb[(size_t)row * HID + (j + 1) * 64 + (s >> 1) * BKF + xgrp * 4];
            }
        }

        // fragments + MFMA, slab 0 then slab 1 (= kc 2j, 2j+1: order preserved)
        #pragma unroll
        for (int sl = 0; sl < 2; sl++) {
            f16x8 Ah[2], Al[2], Bh[4], Bl[4];
            #pragma unroll
            for (int mi = 0; mi < 2; mi++) {
                const unsigned char* p = &Xs[sl][(waveM + mi * 16 + m16) * ROWB + q * 16];
                Ah[mi] = *(const f16x8*)p;
                Al[mi] = *(const f16x8*)(p + 80);
            }
            #pragma unroll
            for (int ni = 0; ni < 4; ni++) {
                const int row = waveN + ni * 16 + m16;
                const unsigned char* pr = &Ws[sl][row * 128];
                const int r7 = row & 7;
                Bh[ni] = *(const f16x8*)(pr + ((q ^ r7) * 16));
                Bl[ni] = *(const f16x8*)(pr + (((4 | q) ^ r7) * 16));
            }
            #pragma unroll
            for (int mi = 0; mi < 2; mi++)
                #pragma unroll
                for (int ni = 0; ni < 4; ni++) {
                    accH[mi][ni] = __builtin_amdgcn_mfma_f32_16x16x32_f16(Ah[mi], Bh[ni], accH[mi][ni], 0, 0, 0);
                    accC[mi][ni] = __builtin_amdgcn_mfma_f32_16x16x32_f16(Ah[mi], Bl[ni], accC[mi][ni], 0, 0, 0);
                    accC[mi][ni] = __builtin_amdgcn_mfma_f32_16x16x32_f16(Al[mi], Bh[ni], accC[mi][ni], 0, 0, 0);
                }
        }
    }

    // C/D layout (verified m89/m91): col = lane&15, row = q*4 + reg
    #pragma unroll
    for (int mi = 0; mi < 2; mi++)
        #pragma unroll
        for (int ni = 0; ni < 4; ni++) {
            const int e = e0 + waveN + ni * 16 + m16;
            #pragma unroll
            for (int r = 0; r < 4; r++) {
                const int token = tok0 + waveM + mi * 16 + q * 4 + r;
                logits[(size_t)token * NEXP + e] =
                    (accH[mi][ni][r] + accC[mi][ni][r] * (1.f / 4096.f)) * (1.f / 64.f);
            }
        }
}

// ================== Fallback GEMM (round-3, verified): X+W converted in-kernel ==================

__launch_bounds__(256, 1)
__global__ void gemm_kernel(const float* __restrict__ X,
                            const float* __restrict__ W,
                            float* __restrict__ logits)
{
    __shared__ __align__(16) unsigned char Xs[BM * ROWB];
    __shared__ __align__(16) unsigned char Ws[BN * ROWB];

    const int tid  = threadIdx.x;
    const int lane = tid & 63;
    const int wave = tid >> 6;

    const int n_grp = blockIdx.x & 3;
    const int m_grp = blockIdx.x >> 2;
    const int tok0  = m_grp * BM;
    const int e0    = n_grp * BN;

    const int waveM = (wave >> 1) * 64;
    const int waveN = (wave & 1) * 64;
    const int m16   = lane & 15;
    const int q     = lane >> 4;

    const float* Xb = X + (size_t)tok0 * HID;
    const float* Wb = W + (size_t)e0 * HID;

    float4 px[4], pw[4];
    #pragma unroll
    for (int s = 0; s < 4; s++) {
        const int flat = s * 256 + tid;
        const int row = flat >> 3, grp = flat & 7;
        px[s] = *(const float4*)&Xb[(size_t)row * HID + grp * 4];
        pw[s] = *(const float4*)&Wb[(size_t)row * HID + grp * 4];
    }

    f32x4 accH[4][4], accC[4][4];
    #pragma unroll
    for (int mi = 0; mi < 4; mi++)
        #pragma unroll
        for (int ni = 0; ni < 4; ni++) { accH[mi][ni] = (f32x4)0.f; accC[mi][ni] = (f32x4)0.f; }

    #pragma unroll 1
    for (int k0 = 0; k0 < HID; k0 += BKF) {
        #pragma unroll
        for (int s = 0; s < 4; s++) {
            const int flat = s * 256 + tid;
            const int row = flat >> 3, grp = flat & 7;
            uint2 h, l;
            cvt4(px[s], h, l);
            *(uint2*)(Xs + row * ROWB + grp * 8)      = h;
            *(uint2*)(Xs + row * ROWB + 80 + grp * 8) = l;
            const float4 w64 = make_float4(pw[s].x * 64.f, pw[s].y * 64.f,
                                           pw[s].z * 64.f, pw[s].w * 64.f);
            cvt4(w64, h, l);
            *(uint2*)(Ws + row * ROWB + grp * 8)      = h;
            *(uint2*)(Ws + row * ROWB + 80 + grp * 8) = l;
        }
        __syncthreads();

        if (k0 + BKF < HID) {
            #pragma unroll
            for (int s = 0; s < 4; s++) {
                const int flat = s * 256 + tid;
                const int row = flat >> 3, grp = flat & 7;
                px[s] = *(const float4*)&Xb[(size_t)row * HID + (k0 + BKF) + grp * 4];
                pw[s] = *(const float4*)&Wb[(size_t)row * HID + (k0 + BKF) + grp * 4];
            }
        }

        f16x8 Ah[4], Al[4], Bh[4], Bl[4];
        #pragma unroll
        for (int mi = 0; mi < 4; mi++) {
            const unsigned char* p = Xs + (waveM + mi * 16 + m16) * ROWB + q * 16;
            Ah[mi] = *(const f16x8*)p;
            Al[mi] = *(const f16x8*)(p + 80);
        }
        #pragma unroll
        for (int ni = 0; ni < 4; ni++) {
            const unsigned char* p = Ws + (waveN + ni * 16 + m16) * ROWB + q * 16;
            Bh[ni] = *(const f16x8*)p;
            Bl[ni] = *(const f16x8*)(p + 80);
        }

        #pragma unroll
        for (int mi = 0; mi < 4; mi++)
            #pragma unroll
            for (int ni = 0; ni < 4; ni++) {
                accH[mi][ni] = __builtin_amdgcn_mfma_f32_16x16x32_f16(Ah[mi], Bh[ni], accH[mi][ni], 0, 0, 0);
                accC[mi][ni] = __builtin_amdgcn_mfma_f32_16x16x32_f16(Ah[mi], Bl[ni], accC[mi][ni], 0, 0, 0);
                accC[mi][ni] = __builtin_amdgcn_mfma_f32_16x16x32_f16(Al[mi], Bh[ni], accC[mi][ni], 0, 0, 0);
            }
        __syncthreads();
    }

    #pragma unroll
    for (int mi = 0; mi < 4; mi++)
        #pragma unroll
        for (int ni = 0; ni < 4; ni++) {
            const int e = e0 + waveN + ni * 16 + m16;
            #pragma unroll
            for (int r = 0; r < 4; r++) {
                const int token = tok0 + waveM + mi * 16 + q * 4 + r;
                logits[(size_t)token * NEXP + e] =
                    (accH[mi][ni][r] + accC[mi][ni][r] * (1.f / 4096.f)) * (1.f / 64.f);
            }
        }
}

// ================== Kernel 2: softmax + biased top-12, 1 token/wave ==================
// Round-7 variant (verified rounds 3/5): per-lane running max-key lk; winning
// lane clears its slot (sentinel 0 < every real key) and rebuilds lk.
// Selection math identical to round 1.

__launch_bounds__(256, 4)
__global__ void topk_kernel(const float* __restrict__ logits,
                            const float* __restrict__ bias,
                            float* __restrict__ out)
{
    const int lane = threadIdx.x & 63;
    const int wave = threadIdx.x >> 6;
    const int tok  = blockIdx.x * 4 + wave;

    const float4 bs0 = *(const float4*)&bias[4 * lane];
    const float4 bs1 = *(const float4*)&bias[256 + 4 * lane];
    const float br[8] = {bs0.x, bs0.y, bs0.z, bs0.w, bs1.x, bs1.y, bs1.z, bs1.w};

    const float4 z0 = *(const float4*)&logits[(size_t)tok * NEXP + 4 * lane];
    const float4 z1 = *(const float4*)&logits[(size_t)tok * NEXP + 256 + 4 * lane];
    float z[8] = {z0.x, z0.y, z0.z, z0.w, z1.x, z1.y, z1.z, z1.w};

    float m = z[0];
    #pragma unroll
    for (int j = 1; j < 8; j++) m = fmaxf(m, z[j]);
    #pragma unroll
    for (int off = 32; off >= 1; off >>= 1) m = fmaxf(m, __shfl_xor(m, off));

    float p[8];
    float s = 0.f;
    #pragma unroll
    for (int j = 0; j < 8; j++) { p[j] = expf(z[j] - m); s += p[j]; }
    #pragma unroll
    for (int off = 32; off >= 1; off >>= 1) s += __shfl_xor(s, off);
    const float inv = 1.f / s;

    float pb[8];
    unsigned long long kj[8];
    #pragma unroll
    for (int j = 0; j < 8; j++) {
        pb[j] = p[j] * inv;
        const int e = (j < 4) ? (4 * lane + j) : (256 + 4 * lane + (j - 4));
        kj[j] = ((unsigned long long)fkey(pb[j] + br[j]) << 32) |
                (unsigned long long)(unsigned int)(1023 - e);
    }
    unsigned long long lk = kj[0];
    #pragma unroll
    for (int j = 1; j < 8; j++) lk = (kj[j] > lk) ? kj[j] : lk;

    for (int kk = 0; kk < TOPK; kk++) {
        unsigned long long key = lk;
        #pragma unroll
        for (int off = 32; off >= 1; off >>= 1) {
            unsigned long long o = __shfl_xor(key, off);
            key = (o > key) ? o : key;
        }
        const int estar = 1023 - (int)(unsigned int)(key & 0xffffffffull);

        int lstar, jstar;
        if (estar < 256) { lstar = estar >> 2;         jstar = estar & 3; }
        else             { lstar = (estar - 256) >> 2; jstar = 4 + ((estar - 256) & 3); }

        const float pj   = pick8(pb, jstar);
        const float psel = __shfl(pj, lstar);

        if (lane == lstar) {
            if (jstar == 0) kj[0] = 0ull;
            if (jstar == 1) kj[1] = 0ull;
            if (jstar == 2) kj[2] = 0ull;
            if (jstar == 3) kj[3] = 0ull;
            if (jstar == 4) kj[4] = 0ull;
            if (jstar == 5) kj[5] = 0ull;
            if (jstar == 6) kj[6] = 0ull;
            if (jstar == 7) kj[7] = 0ull;
            unsigned long long nl = kj[0];
            #pragma unroll
            for (int j = 1; j < 8; j++) nl = (kj[j] > nl) ? kj[j] : nl;
            lk = nl;
        }

        if (lane == 0) {
            out[(size_t)tok * TOPK + kk] = psel * RSCALE;
            out[(size_t)T_TOKENS * TOPK + (size_t)tok * TOPK + kk] = (float)estar;
        }
    }
}

// ================== Fallback: round-1 fused fp32 kernel (verified) ==================

#define TM   32
#define BK   16
#define EPAD (NEXP + 4)
#define XPAD 36

__launch_bounds__(256, 1)
__global__ void router_kernel(const float* __restrict__ X,
                              const float* __restrict__ W,
                              const float* __restrict__ bias,
                              float* __restrict__ out)
{
    __shared__ float Wsh[BK][EPAD];
    __shared__ float Xsh[BK][XPAD];

    const int tid  = threadIdx.x;
    const int lane = tid & 63;
    const int wave = tid >> 6;
    const int tok0 = blockIdx.x * TM;

    float acc[8][8];
    #pragma unroll
    for (int i = 0; i < 8; i++)
        #pragma unroll
        for (int j = 0; j < 8; j++) acc[i][j] = 0.f;

    const int xt = tid >> 4;
    const int xk = tid & 15;

    for (int k0 = 0; k0 < HID; k0 += BK) {
        #pragma unroll
        for (int r = 0; r < 2; r++) {
            int t = r * 16 + xt;
            Xsh[xk][t] = X[(size_t)(tok0 + t) * HID + k0 + xk];
        }
        #pragma unroll
        for (int r = 0; r < 8; r++) {
            int flat4 = r * 256 + tid;
            int e  = flat4 >> 2;
            int kq = (flat4 & 3) * 4;
            const float4 wv = *(const float4*)&W[(size_t)e * HID + k0 + kq];
            Wsh[kq + 0][e] = wv.x;
            Wsh[kq + 1][e] = wv.y;
            Wsh[kq + 2][e] = wv.z;
            Wsh[kq + 3][e] = wv.w;
        }
        __syncthreads();

        #pragma unroll
        for (int k = 0; k < BK; k++) {
            float4 b0 = *(const float4*)&Wsh[k][4 * lane];
            float4 b1 = *(const float4*)&Wsh[k][256 + 4 * lane];
            float4 a0 = *(const float4*)&Xsh[k][wave * 8];
            float4 a1 = *(const float4*)&Xsh[k][wave * 8 + 4];
            float a[8] = {a0.x, a0.y, a0.z, a0.w, a1.x, a1.y, a1.z, a1.w};
            float b[8] = {b0.x, b0.y, b0.z, b0.w, b1.x, b1.y, b1.z, b1.w};
            #pragma unroll
            for (int i = 0; i < 8; i++)
                #pragma unroll
                for (int j = 0; j < 8; j++)
                    acc[i][j] = fmaf(a[i], b[j], acc[i][j]);
        }
        __syncthreads();
    }

    const float4 bs0 = *(const float4*)&bias[4 * lane];
    const float4 bs1 = *(const float4*)&bias[256 + 4 * lane];
    const float br[8] = {bs0.x, bs0.y, bs0.z, bs0.w, bs1.x, bs1.y, bs1.z, bs1.w};

    for (int i = 0; i < 8; i++) {
        const int tok = tok0 + wave * 8 + i;

        float m = acc[i][0];
        #pragma unroll
        for (int j = 1; j < 8; j++) m = fmaxf(m, acc[i][j]);
        #pragma unroll
        for (int off = 32; off >= 1; off >>= 1) m = fmaxf(m, __shfl_xor(m, off));

        float p[8];
        float s = 0.f;
        #pragma unroll
        for (int j = 0; j < 8; j++) { p[j] = expf(acc[i][j] - m); s += p[j]; }
        #pragma unroll
        for (int off = 32; off >= 1; off >>= 1) s += __shfl_xor(s, off);
        const float inv = 1.f / s;

        float pb[8], bb[8];
        #pragma unroll
        for (int j = 0; j < 8; j++) {
            pb[j] = p[j] * inv;
            bb[j] = pb[j] + br[j];
        }

        for (int kk = 0; kk < TOPK; kk++) {
            unsigned long long key = 0ull;
            #pragma unroll
            for (int j = 0; j < 8; j++) {
                int e = (j < 4) ? (4 * lane + j) : (256 + 4 * lane + (j - 4));
                unsigned long long k64 =
                    ((unsigned long long)fkey(bb[j]) << 32) |
                    (unsigned long long)(unsigned int)(1023 - e);
                key = (k64 > key) ? k64 : key;
            }
            #pragma unroll
            for (int off = 32; off >= 1; off >>= 1) {
                unsigned long long o = __shfl_xor(key, off);
                key = (o > key) ? o : key;
            }
            const int estar = 1023 - (int)(unsigned int)(key & 0xffffffffull);

            int lstar, jstar;
            if (estar < 256) { lstar = estar >> 2;         jstar = estar & 3; }
            else             { lstar = (estar - 256) >> 2; jstar = 4 + ((estar - 256) & 3); }

            const float pj   = pick8(pb, jstar);
            const float psel = __shfl(pj, lstar);

            if (lane == lstar) {
                if (jstar == 0) bb[0] = -INFINITY;
                if (jstar == 1) bb[1] = -INFINITY;
                if (jstar == 2) bb[2] = -INFINITY;
                if (jstar == 3) bb[3] = -INFINITY;
                if (jstar == 4) bb[4] = -INFINITY;
                if (jstar == 5) bb[5] = -INFINITY;
                if (jstar == 6) bb[6] = -INFINITY;
                if (jstar == 7) bb[7] = -INFINITY;
            }

            if (lane == 0) {
                out[(size_t)tok * TOPK + kk] = psel * RSCALE;
                out[(size_t)T_TOKENS * TOPK + (size_t)tok * TOPK + kk] = (float)estar;
            }
        }
    }
}

// ================== launcher ==================

extern "C" void kernel_launch(void* const* d_in, const int* in_sizes, int n_in,
                              void* d_out, int out_size, void* d_ws, size_t ws_size,
                              hipStream_t stream)
{
    const float* X    = (const float*)d_in[0];   // [8192, 4096]
    const float* W    = (const float*)d_in[1];   // [512, 4096]
    const float* bias = (const float*)d_in[2];   // [512]
    float* out = (float*)d_out;

    const size_t logits_bytes = (size_t)T_TOKENS * NEXP * sizeof(float);   // 16 MB
    const size_t wp_bytes     = (size_t)NEXP * HID * 4;                    // 8 MB (2 fp16 planes)

    if (ws_size >= logits_bytes + wp_bytes) {
        float* logits = (float*)d_ws;
        uint4* Wp     = (uint4*)((char*)d_ws + logits_bytes);
        wconv_kernel<<<dim3(2048), dim3(256), 0, stream>>>(W, Wp);
        gemm2_kernel<<<dim3(512), dim3(256), 0, stream>>>(X, Wp, logits);
        topk_kernel<<<dim3(T_TOKENS / 4), dim3(256), 0, stream>>>(logits, bias, out);
    } else if (ws_size >= logits_bytes) {
        float* logits = (float*)d_ws;
        gemm_kernel<<<dim3(256), dim3(256), 0, stream>>>(X, W, logits);
        topk_kernel<<<dim3(T_TOKENS / 4), dim3(256), 0, stream>>>(logits, bias, out);
    } else {
        router_kernel<<<dim3(T_TOKENS / TM), dim3(256), 0, stream>>>(X, W, bias, out);
    }
}